// Round 1
// baseline (281.108 us; speedup 1.0000x reference)
//
#include <hip/hip_runtime.h>
#include <cstdint>
#include <cstddef>

#define BM 128
#define BN 128
#define BK 32

using bf16x8 = __attribute__((ext_vector_type(8))) short;
using f32x4  = __attribute__((ext_vector_type(4))) float;

__device__ __forceinline__ unsigned short f2bf(float f) {
  unsigned int u = __builtin_bit_cast(unsigned int, f);
  u += 0x7FFFu + ((u >> 16) & 1u);   // round-to-nearest-even
  return (unsigned short)(u >> 16);
}
__device__ __forceinline__ float bf2f(unsigned int h16) {
  unsigned int u = h16 << 16;
  return __builtin_bit_cast(float, u);
}

__device__ __forceinline__ void gl_lds16(const void* g, void* l) {
  __builtin_amdgcn_global_load_lds(
      (const __attribute__((address_space(1))) unsigned int*)g,
      (__attribute__((address_space(3))) unsigned int*)l,
      16, 0, 0);
}

// C[m,n] = sum_k A[m,k] * B[n,k]   (A: MxK row-major bf16, B: NxK row-major bf16)
// MODE 0: e = exp(scale[n]/(sqrt(max(x2[m]-2c+p2[n],0))+0.1)) -> bf16 store   (aux0=x2, aux1=p2, aux2=scale)
// MODE 1: bf16 store of c*rdenom[m]                                           (aux0=rdenom)
// MODE 2: fp32 store of c + bias[n]                                           (aux0=b_o)
// MODE 3: bf16 store of c + bias[m]                                           (aux0=b_v)
template<int MODE>
__global__ void gemm_bt(const unsigned short* __restrict__ A,
                        const unsigned short* __restrict__ B,
                        void* __restrict__ Cv,
                        int M, int N, int K,
                        const float* __restrict__ aux0,
                        const float* __restrict__ aux1,
                        const float* __restrict__ aux2)
{
  __shared__ unsigned short As[BM * BK];
  __shared__ unsigned short Bs[BN * BK];

  const int tid  = threadIdx.x;
  const int lane = tid & 63;
  const int wv   = tid >> 6;
  const int wm   = (wv >> 1) * 64;
  const int wn   = (wv & 1) * 64;
  const int l16  = lane & 15;
  const int quad = lane >> 4;

  const int n0 = blockIdx.x * BN;
  const int m0 = blockIdx.y * BM;

  f32x4 acc[4][4];
#pragma unroll
  for (int i = 0; i < 4; ++i)
#pragma unroll
    for (int j = 0; j < 4; ++j) {
      f32x4 z = {0.f, 0.f, 0.f, 0.f};
      acc[i][j] = z;
    }

  // staging: 512 16B-chunks per tile (128 rows x 4 chunks); tid -> chunk, tid+256 -> chunk
  const int row0 = tid >> 2;
  const int col8 = (tid & 3) * 8;

  const unsigned short* Ag0 = A + (size_t)(m0 + row0) * K + col8;
  const unsigned short* Ag1 = A + (size_t)(m0 + row0 + 64) * K + col8;
  const unsigned short* Bg0 = B + (size_t)(n0 + row0) * K + col8;
  const unsigned short* Bg1 = B + (size_t)(n0 + row0 + 64) * K + col8;
  unsigned short* Al0 = &As[(size_t)tid * 8];
  unsigned short* Al1 = &As[(size_t)(tid + 256) * 8];
  unsigned short* Bl0 = &Bs[(size_t)tid * 8];
  unsigned short* Bl1 = &Bs[(size_t)(tid + 256) * 8];

  for (int kc = 0; kc < K; kc += BK) {
    __syncthreads();
    gl_lds16(Ag0 + kc, Al0);
    gl_lds16(Ag1 + kc, Al1);
    gl_lds16(Bg0 + kc, Bl0);
    gl_lds16(Bg1 + kc, Bl1);
    __syncthreads();

    bf16x8 af[4], bfr[4];
#pragma unroll
    for (int mi = 0; mi < 4; ++mi)
      af[mi] = *(const bf16x8*)&As[(wm + mi * 16 + l16) * BK + quad * 8];
#pragma unroll
    for (int ni = 0; ni < 4; ++ni)
      bfr[ni] = *(const bf16x8*)&Bs[(wn + ni * 16 + l16) * BK + quad * 8];
#pragma unroll
    for (int mi = 0; mi < 4; ++mi)
#pragma unroll
      for (int ni = 0; ni < 4; ++ni)
        acc[mi][ni] = __builtin_amdgcn_mfma_f32_16x16x32_bf16(af[mi], bfr[ni], acc[mi][ni], 0, 0, 0);
  }

  // ---- epilogue ----
  float p2v[4], scv[4], bnv[4];
  if (MODE == 0) {
#pragma unroll
    for (int ni = 0; ni < 4; ++ni) {
      const int n = n0 + wn + ni * 16 + l16;
      p2v[ni] = aux1[n];
      scv[ni] = aux2[n];
    }
  }
  if (MODE == 2) {
#pragma unroll
    for (int ni = 0; ni < 4; ++ni) bnv[ni] = aux0[n0 + wn + ni * 16 + l16];
  }

#pragma unroll
  for (int mi = 0; mi < 4; ++mi) {
#pragma unroll
    for (int r = 0; r < 4; ++r) {
      const int m = m0 + wm + mi * 16 + quad * 4 + r;
      float rowa = 0.f;
      if (MODE == 0 || MODE == 1 || MODE == 3) rowa = aux0[m];
#pragma unroll
      for (int ni = 0; ni < 4; ++ni) {
        const int n = n0 + wn + ni * 16 + l16;
        float v = acc[mi][ni][r];
        if (MODE == 0) {
          float sq   = fmaxf(rowa - 2.0f * v + p2v[ni], 0.0f);
          float dist = sqrtf(sq);
          float e    = __expf(scv[ni] / (dist + 0.1f));
          ((unsigned short*)Cv)[(size_t)m * N + n] = f2bf(e);
        } else if (MODE == 1) {
          ((unsigned short*)Cv)[(size_t)m * N + n] = f2bf(v * rowa);
        } else if (MODE == 2) {
          ((float*)Cv)[(size_t)m * N + n] = v + bnv[ni];
        } else {
          ((unsigned short*)Cv)[(size_t)m * N + n] = f2bf(v + rowa);
        }
      }
    }
  }
}

// fp32 -> bf16 convert, 4 elems/thread
__global__ void cvt_bf16(const float* __restrict__ in, unsigned short* __restrict__ out, int n4) {
  int i = blockIdx.x * 256 + threadIdx.x;
  if (i < n4) {
    float4 v = ((const float4*)in)[i];
    ushort4 o;
    o.x = f2bf(v.x); o.y = f2bf(v.y); o.z = f2bf(v.z); o.w = f2bf(v.w);
    ((ushort4*)out)[i] = o;
  }
}

// per-row sum of squares, 512 cols, one wave per row, 4 rows/block
__global__ void row_sumsq(const float* __restrict__ X, float* __restrict__ out) {
  const int lane = threadIdx.x & 63;
  const int wv   = threadIdx.x >> 6;
  const int r    = blockIdx.x * 4 + wv;
  const float4 a = *(const float4*)(X + (size_t)r * 512 + lane * 4);
  const float4 b = *(const float4*)(X + (size_t)r * 512 + 256 + lane * 4);
  float s = a.x*a.x + a.y*a.y + a.z*a.z + a.w*a.w
          + b.x*b.x + b.y*b.y + b.z*b.z + b.w*b.w;
#pragma unroll
  for (int off = 32; off > 0; off >>= 1) s += __shfl_down(s, off, 64);
  if (lane == 0) out[r] = s;
}

// rdenom[m] = 1 / sum_n E[m,n]   (E: M x 4096 bf16)
__global__ void row_sum_exp(const unsigned short* __restrict__ E, float* __restrict__ rd) {
  const int m = blockIdx.x;
  const uint4* row = (const uint4*)(E + (size_t)m * 4096);
  float s = 0.f;
  for (int i = threadIdx.x; i < 512; i += 256) {
    uint4 u = row[i];
    s += bf2f(u.x & 0xFFFFu) + bf2f(u.x >> 16)
       + bf2f(u.y & 0xFFFFu) + bf2f(u.y >> 16)
       + bf2f(u.z & 0xFFFFu) + bf2f(u.z >> 16)
       + bf2f(u.w & 0xFFFFu) + bf2f(u.w >> 16);
  }
#pragma unroll
  for (int off = 32; off > 0; off >>= 1) s += __shfl_down(s, off, 64);
  __shared__ float ws4[4];
  if ((threadIdx.x & 63) == 0) ws4[threadIdx.x >> 6] = s;
  __syncthreads();
  if (threadIdx.x == 0) rd[m] = 1.0f / (ws4[0] + ws4[1] + ws4[2] + ws4[3]);
}

extern "C" void kernel_launch(void* const* d_in, const int* in_sizes, int n_in,
                              void* d_out, int out_size, void* d_ws, size_t ws_size,
                              hipStream_t stream) {
  const float* x         = (const float*)d_in[0];
  const float* positions = (const float*)d_in[1];
  const float* scale     = (const float*)d_in[2];
  const float* w_v       = (const float*)d_in[3];
  const float* b_v       = (const float*)d_in[4];
  const float* w_o       = (const float*)d_in[5];
  const float* b_o       = (const float*)d_in[6];
  float* out = (float*)d_out;

  const int M = 8192, N = 4096, D = 512;

  char* ws = (char*)d_ws;
  unsigned short* xb  = (unsigned short*)ws; ws += (size_t)M * D * 2;   // x bf16
  unsigned short* pb  = (unsigned short*)ws; ws += (size_t)N * D * 2;   // positions bf16
  unsigned short* wvb = (unsigned short*)ws; ws += (size_t)D * D * 2;   // w_v bf16
  unsigned short* wob = (unsigned short*)ws; ws += (size_t)D * D * 2;   // w_o bf16
  unsigned short* vT  = (unsigned short*)ws; ws += (size_t)D * N * 2;   // values^T (D x N) bf16
  unsigned short* Eb  = (unsigned short*)ws; ws += (size_t)M * N * 2;   // exp(interactions) bf16
  unsigned short* ob  = (unsigned short*)ws; ws += (size_t)M * D * 2;   // attn @ values, bf16
  float* x2 = (float*)ws; ws += (size_t)M * 4;
  float* p2 = (float*)ws; ws += (size_t)N * 4;
  float* rd = (float*)ws; ws += (size_t)M * 4;

  // conversions + row norms
  cvt_bf16<<<(M * D / 4 + 255) / 256, 256, 0, stream>>>(x, xb, M * D / 4);
  cvt_bf16<<<(N * D / 4 + 255) / 256, 256, 0, stream>>>(positions, pb, N * D / 4);
  cvt_bf16<<<(D * D / 4 + 255) / 256, 256, 0, stream>>>(w_v, wvb, D * D / 4);
  cvt_bf16<<<(D * D / 4 + 255) / 256, 256, 0, stream>>>(w_o, wob, D * D / 4);
  row_sumsq<<<M / 4, 256, 0, stream>>>(x, x2);
  row_sumsq<<<N / 4, 256, 0, stream>>>(positions, p2);

  // values^T[d,n] = sum_k w_v[d,k] * positions[n,k] + b_v[d]
  gemm_bt<3><<<dim3(N / BN, D / BM), 256, 0, stream>>>(wvb, pb, vT, D, N, D, b_v, nullptr, nullptr);

  // E[m,n] = exp(scale[n] / (dist(m,n) + 0.1))
  gemm_bt<0><<<dim3(N / BN, M / BM), 256, 0, stream>>>(xb, pb, Eb, M, N, D, x2, p2, scale);

  // rdenom[m] = 1 / sum_n E[m,n]
  row_sum_exp<<<M, 256, 0, stream>>>(Eb, rd);

  // ob[m,d] = (sum_n E[m,n] * values[n,d]) * rdenom[m]
  gemm_bt<1><<<dim3(D / BN, M / BM), 256, 0, stream>>>(Eb, vT, ob, M, D, N, rd, nullptr, nullptr);

  // out[m,d] = sum_k ob[m,k] * w_o[d,k] + b_o[d]
  gemm_bt<2><<<dim3(D / BN, M / BM), 256, 0, stream>>>(ob, wob, out, M, D, D, b_o, nullptr, nullptr);
}